// Round 1
// baseline (755.646 us; speedup 1.0000x reference)
//
#include <hip/hip_runtime.h>
#include <math.h>

#define NEG_SLOPE 0.2f

// ---------------- CSR build ----------------
__global__ void deg_kernel(const int* __restrict__ ei, int* __restrict__ deg, int E) {
    int e = blockIdx.x * blockDim.x + threadIdx.x;
    if (e < E) atomicAdd(&deg[ei[E + e]], 1);
}

__global__ __launch_bounds__(1024) void scan_kernel(const int* __restrict__ deg,
        int* __restrict__ rowptr, int* __restrict__ cursor, int n) {
    __shared__ int tmp[1024];
    int t = threadIdx.x;
    int running = 0;
    for (int base = 0; base < n; base += 1024) {
        int v = (base + t < n) ? deg[base + t] : 0;
        tmp[t] = v;
        __syncthreads();
        for (int off = 1; off < 1024; off <<= 1) {
            int x = (t >= off) ? tmp[t - off] : 0;
            __syncthreads();
            tmp[t] += x;
            __syncthreads();
        }
        int excl = tmp[t] - v + running;
        if (base + t < n) { rowptr[base + t] = excl; cursor[base + t] = excl; }
        running += tmp[1023];
        __syncthreads();
    }
    if (t == 0) rowptr[n] = running;
}

__global__ void scatter_kernel(const int* __restrict__ ei, int* __restrict__ cursor,
                               int* __restrict__ adj, int E) {
    int e = blockIdx.x * blockDim.x + threadIdx.x;
    if (e < E) {
        int d = ei[E + e];
        int pos = atomicAdd(&cursor[d], 1);
        adj[pos] = ei[e];   // store src node id
    }
}

// ---------------- fp32 GEMM: C[n x 256] = A[n x 256] @ W^T (W row-major 256x256) ----------------
// BM=128, BN=64, BK=32, 256 threads (16x16), each thread 8x4 outputs.
__global__ __launch_bounds__(256) void gemm_xwT(const float* __restrict__ A,
        const float* __restrict__ W, float* __restrict__ C, int n) {
    __shared__ float As[32 * 128];  // k-major [k][row]
    __shared__ float Bs[32 * 64];   // k-major [k][col]
    const int t = threadIdx.x;
    const int tx = t & 15, ty = t >> 4;
    const int brow = blockIdx.x * 128;
    const int bcol = blockIdx.y * 64;

    float acc[8][4];
#pragma unroll
    for (int i = 0; i < 8; i++)
#pragma unroll
        for (int j = 0; j < 4; j++) acc[i][j] = 0.f;

    for (int kt = 0; kt < 256; kt += 32) {
#pragma unroll
        for (int p = 0; p < 4; p++) {
            int i = t + 256 * p;
            int row = i >> 3, c4 = i & 7;
            int gr = brow + row;
            float4 v = make_float4(0.f, 0.f, 0.f, 0.f);
            if (gr < n) v = *(const float4*)(A + (size_t)gr * 256 + kt + c4 * 4);
            As[(c4 * 4 + 0) * 128 + row] = v.x;
            As[(c4 * 4 + 1) * 128 + row] = v.y;
            As[(c4 * 4 + 2) * 128 + row] = v.z;
            As[(c4 * 4 + 3) * 128 + row] = v.w;
        }
#pragma unroll
        for (int p = 0; p < 2; p++) {
            int i = t + 256 * p;
            int col = i >> 3, c4 = i & 7;
            float4 v = *(const float4*)(W + (size_t)(bcol + col) * 256 + kt + c4 * 4);
            Bs[(c4 * 4 + 0) * 64 + col] = v.x;
            Bs[(c4 * 4 + 1) * 64 + col] = v.y;
            Bs[(c4 * 4 + 2) * 64 + col] = v.z;
            Bs[(c4 * 4 + 3) * 64 + col] = v.w;
        }
        __syncthreads();
#pragma unroll
        for (int kk = 0; kk < 32; kk++) {
            float4 a0 = *(const float4*)(As + kk * 128 + ty * 8);
            float4 a1 = *(const float4*)(As + kk * 128 + ty * 8 + 4);
            float4 b  = *(const float4*)(Bs + kk * 64 + tx * 4);
            float av[8] = {a0.x, a0.y, a0.z, a0.w, a1.x, a1.y, a1.z, a1.w};
            float bv[4] = {b.x, b.y, b.z, b.w};
#pragma unroll
            for (int i = 0; i < 8; i++)
#pragma unroll
                for (int j = 0; j < 4; j++)
                    acc[i][j] = fmaf(av[i], bv[j], acc[i][j]);
        }
        __syncthreads();
    }
#pragma unroll
    for (int i = 0; i < 8; i++) {
        int row = brow + ty * 8 + i;
        if (row < n) {
            float4 v = make_float4(acc[i][0], acc[i][1], acc[i][2], acc[i][3]);
            *(float4*)(C + (size_t)row * 256 + bcol + tx * 4) = v;
        }
    }
}

// ---------------- per-node attention scalars: a_dst = h.att[:256], a_src = h.att[256:] ----------------
__global__ __launch_bounds__(256) void node_att(const float* __restrict__ H,
        const float* __restrict__ att, float* __restrict__ a_dst,
        float* __restrict__ a_src, int n) {
    int w = threadIdx.x >> 6, lane = threadIdx.x & 63;
    int node = blockIdx.x * 4 + w;
    if (node >= n) return;
    float4 h4 = *(const float4*)(H + (size_t)node * 256 + lane * 4);
    float4 aL = *(const float4*)(att + lane * 4);
    float4 aH = *(const float4*)(att + 256 + lane * 4);
    float ai = h4.x * aL.x + h4.y * aL.y + h4.z * aL.z + h4.w * aL.w;
    float aj = h4.x * aH.x + h4.y * aH.y + h4.z * aH.z + h4.w * aH.w;
#pragma unroll
    for (int off = 32; off; off >>= 1) {
        ai += __shfl_xor(ai, off);
        aj += __shfl_xor(aj, off);
    }
    if (lane == 0) { a_dst[node] = ai; a_src[node] = aj; }
}

// ---------------- fused segment-softmax + weighted aggregation, one wave per dst node ----------------
__global__ __launch_bounds__(256) void gat_agg(const float* __restrict__ H,
        const float* __restrict__ a_dst, const float* __restrict__ a_src,
        const int* __restrict__ rowptr, const int* __restrict__ adj,
        const float* __restrict__ bias, float* __restrict__ OUT, int n) {
    int w = threadIdx.x >> 6, lane = threadIdx.x & 63;
    int node = blockIdx.x * 4 + w;
    if (node >= n) return;
    int beg = rowptr[node], end = rowptr[node + 1];
    float ai = a_dst[node];

    // pass 1: segment max
    float m = -3.4e38f;
    for (int j = beg + lane; j < end; j += 64) {
        float e = ai + a_src[adj[j]];
        e = (e > 0.f) ? e : NEG_SLOPE * e;
        m = fmaxf(m, e);
    }
#pragma unroll
    for (int off = 32; off; off >>= 1) m = fmaxf(m, __shfl_xor(m, off));

    // pass 2: sum of exp and weighted feature accumulation
    float ssum = 0.f;
    float4 acc = make_float4(0.f, 0.f, 0.f, 0.f);
    for (int j0 = beg; j0 < end; j0 += 64) {
        int cnt = min(64, end - j0);
        int sidx = 0;
        float e = 0.f;
        if (lane < cnt) {
            sidx = adj[j0 + lane];
            float t = ai + a_src[sidx];
            e = (t > 0.f) ? t : NEG_SLOPE * t;
        }
        for (int j = 0; j < cnt; j++) {
            float ej = __shfl(e, j);
            int sj = __shfl(sidx, j);
            float wgt = expf(ej - m);
            ssum += wgt;
            float4 hv = *(const float4*)(H + (size_t)sj * 256 + lane * 4);
            acc.x = fmaf(wgt, hv.x, acc.x);
            acc.y = fmaf(wgt, hv.y, acc.y);
            acc.z = fmaf(wgt, hv.z, acc.z);
            acc.w = fmaf(wgt, hv.w, acc.w);
        }
    }
    float inv = 1.f / (ssum + 1e-16f);
    float4 b4 = *(const float4*)(bias + lane * 4);
    float4 o;
    o.x = acc.x * inv + b4.x;
    o.y = acc.y * inv + b4.y;
    o.z = acc.z * inv + b4.z;
    o.w = acc.w * inv + b4.w;
    *(float4*)(OUT + (size_t)node * 256 + lane * 4) = o;
}

// ---------------- relu + global max pool (batch is sorted) ----------------
__global__ __launch_bounds__(256) void pool_kernel(const float* __restrict__ X,
        const int* __restrict__ batch, float* __restrict__ gbuf, int n) {
    int g = blockIdx.x;
    int c = threadIdx.x;
    int lo = 0, hi = n;
    while (lo < hi) { int mid = (lo + hi) >> 1; if (batch[mid] < g) lo = mid + 1; else hi = mid; }
    int start = lo;
    hi = n;
    while (lo < hi) { int mid = (lo + hi) >> 1; if (batch[mid] < g + 1) lo = mid + 1; else hi = mid; }
    int end_ = lo;
    float m = 0.f;  // relu floor
    for (int i = start; i < end_; ++i)
        m = fmaxf(m, X[(size_t)i * 256 + c]);
    gbuf[g * 256 + c] = m;
}

// ---------------- post-MLP + log_softmax, one block per graph ----------------
__global__ __launch_bounds__(256) void final_kernel(const float* __restrict__ gbuf,
        const float* __restrict__ pW1, const float* __restrict__ pb1,
        const float* __restrict__ pW2, const float* __restrict__ pb2,
        float* __restrict__ out) {
    __shared__ float gl[256];
    __shared__ float h1[256];
    int g = blockIdx.x, t = threadIdx.x;
    gl[t] = gbuf[g * 256 + t];
    __syncthreads();
    float acc = pb1[t];
    for (int k = 0; k < 256; k++) acc = fmaf(gl[k], pW1[t * 256 + k], acc);
    h1[t] = acc;
    __syncthreads();
    if (t < 64) {
        float o = pb2[t];
        for (int k = 0; k < 256; k++) o = fmaf(h1[k], pW2[t * 256 + k], o);
        float mx = o;
#pragma unroll
        for (int off = 32; off; off >>= 1) mx = fmaxf(mx, __shfl_xor(mx, off));
        float ex = expf(o - mx);
        float s = ex;
#pragma unroll
        for (int off = 32; off; off >>= 1) s += __shfl_xor(s, off);
        out[g * 64 + t] = o - mx - logf(s);
    }
}

extern "C" void kernel_launch(void* const* d_in, const int* in_sizes, int n_in,
                              void* d_out, int out_size, void* d_ws, size_t ws_size,
                              hipStream_t stream) {
    const float* x     = (const float*)d_in[0];
    const int*   ei    = (const int*)d_in[1];
    const int*   batch = (const int*)d_in[2];
    const float* Ws    = (const float*)d_in[3];
    const float* atts  = (const float*)d_in[4];
    const float* bs    = (const float*)d_in[5];
    const float* pW1   = (const float*)d_in[6];
    const float* pb1   = (const float*)d_in[7];
    const float* pW2   = (const float*)d_in[8];
    const float* pb2   = (const float*)d_in[9];
    float* out = (float*)d_out;

    const int N = in_sizes[0] / 256;
    const int E = in_sizes[1] / 2;
    const int G = out_size / 64;
    const int L = in_sizes[3] / (256 * 256);

    char* ws = (char*)d_ws;
    size_t off = 0;
    auto alloc = [&](size_t bytes) -> char* {
        char* p = ws + off;
        off += (bytes + 255) & ~size_t(255);
        return p;
    };
    float* H      = (float*)alloc((size_t)N * 256 * 4);
    float* XA     = (float*)alloc((size_t)N * 256 * 4);
    float* XB     = (float*)alloc((size_t)N * 256 * 4);
    float* a_dst  = (float*)alloc((size_t)N * 4);
    float* a_src  = (float*)alloc((size_t)N * 4);
    int*   deg    = (int*)alloc((size_t)N * 4);
    int*   rowptr = (int*)alloc((size_t)(N + 1) * 4);
    int*   cursor = (int*)alloc((size_t)N * 4);
    int*   adj    = (int*)alloc((size_t)E * 4);
    float* gbuf   = (float*)alloc((size_t)G * 256 * 4);

    hipMemsetAsync(deg, 0, (size_t)N * 4, stream);
    int eb = (E + 255) / 256;
    deg_kernel<<<eb, 256, 0, stream>>>(ei, deg, E);
    scan_kernel<<<1, 1024, 0, stream>>>(deg, rowptr, cursor, N);
    scatter_kernel<<<eb, 256, 0, stream>>>(ei, cursor, adj, E);

    const float* Xcur = x;
    float* outs[3] = {XA, XB, XA};
    for (int l = 0; l < L; ++l) {
        dim3 ggrid((N + 127) / 128, 4);
        gemm_xwT<<<ggrid, 256, 0, stream>>>(Xcur, Ws + (size_t)l * 256 * 256, H, N);
        node_att<<<(N + 3) / 4, 256, 0, stream>>>(H, atts + (size_t)l * 512, a_dst, a_src, N);
        gat_agg<<<(N + 3) / 4, 256, 0, stream>>>(H, a_dst, a_src, rowptr, adj,
                                                 bs + (size_t)l * 256, outs[l], N);
        Xcur = outs[l];
    }
    pool_kernel<<<G, 256, 0, stream>>>(Xcur, batch, gbuf, N);
    final_kernel<<<G, 256, 0, stream>>>(gbuf, pW1, pb1, pW2, pb2, out);
}

// Round 2
// 443.867 us; speedup vs baseline: 1.7024x; 1.7024x over previous
//
#include <hip/hip_runtime.h>
#include <math.h>

#define NEG_SLOPE 0.2f

typedef __attribute__((ext_vector_type(8))) short s16x8;   // 8 bf16 (4 VGPRs)
typedef __attribute__((ext_vector_type(4))) float f32x4;
typedef unsigned short ushort_t;

__device__ inline ushort_t f2bf(float f) {
    unsigned u = __float_as_uint(f);
    unsigned r = (u + 0x7fff + ((u >> 16) & 1)) >> 16;   // RNE
    return (ushort_t)r;
}

// ---------------- fp32 -> bf16 conversion (4 elems/thread) ----------------
__global__ __launch_bounds__(256) void cvt_kernel(const float* __restrict__ in,
        ushort_t* __restrict__ out, int n4) {
    int i = blockIdx.x * 256 + threadIdx.x;
    if (i < n4) {
        float4 v = ((const float4*)in)[i];
        ushort4 o;
        o.x = f2bf(v.x); o.y = f2bf(v.y); o.z = f2bf(v.z); o.w = f2bf(v.w);
        ((ushort4*)out)[i] = o;
    }
}

// ---------------- CSR build ----------------
__global__ void deg_kernel(const int* __restrict__ ei, int* __restrict__ deg, int E) {
    int e = blockIdx.x * blockDim.x + threadIdx.x;
    if (e < E) atomicAdd(&deg[ei[E + e]], 1);
}

__global__ __launch_bounds__(1024) void scan1(const int* __restrict__ deg,
        int* __restrict__ tscan, int* __restrict__ bsum, int n) {
    __shared__ int ws[16];
    int t = threadIdx.x;
    int gi = blockIdx.x * 1024 + t;
    int v = (gi < n) ? deg[gi] : 0;
    int lane = t & 63, w = t >> 6;
    int s = v;
#pragma unroll
    for (int off = 1; off < 64; off <<= 1) {
        int u = __shfl_up(s, off);
        if (lane >= off) s += u;
    }
    if (lane == 63) ws[w] = s;
    __syncthreads();
    if (w == 0) {
        int x = (lane < 16) ? ws[lane] : 0;
#pragma unroll
        for (int off = 1; off < 16; off <<= 1) {
            int u = __shfl_up(x, off);
            if (lane >= off) x += u;
        }
        if (lane < 16) ws[lane] = x;
    }
    __syncthreads();
    int woff = (w > 0) ? ws[w - 1] : 0;
    if (gi < n) tscan[gi] = woff + s - v;       // exclusive within block
    if (t == 1023) bsum[blockIdx.x] = woff + s; // block total
}

__global__ void scan2(const int* __restrict__ bsum, int* __restrict__ boff,
                      int nb, int* __restrict__ total_out) {
    int lane = threadIdx.x;
    int v = (lane < nb) ? bsum[lane] : 0;
    int s = v;
#pragma unroll
    for (int off = 1; off < 64; off <<= 1) {
        int u = __shfl_up(s, off);
        if (lane >= off) s += u;
    }
    if (lane < nb) boff[lane] = s - v;
    if (lane == 63) *total_out = s;
}

__global__ __launch_bounds__(1024) void scan3(const int* __restrict__ tscan,
        const int* __restrict__ boff, int* __restrict__ rowptr,
        int* __restrict__ cursor, int n) {
    int i = blockIdx.x * 1024 + threadIdx.x;
    if (i < n) {
        int v = tscan[i] + boff[blockIdx.x];
        rowptr[i] = v;
        cursor[i] = v;
    }
}

__global__ void scatter_kernel(const int* __restrict__ ei, int* __restrict__ cursor,
                               int* __restrict__ adj, int E) {
    int e = blockIdx.x * blockDim.x + threadIdx.x;
    if (e < E) {
        int d = ei[E + e];
        int pos = atomicAdd(&cursor[d], 1);
        adj[pos] = ei[e];   // store src node id
    }
}

// ---------------- bf16 MFMA GEMM: C[n x 256] = A @ W^T ----------------
// A bf16 [Mpad][256], W bf16 [256][256] row-major (rows are B columns).
// BM=128, BN=128, BK=32, 256 threads = 4 waves (2x2), each wave 64x64 out.
__global__ __launch_bounds__(256) void gemm_bf16(const ushort_t* __restrict__ A,
        const ushort_t* __restrict__ B, float* __restrict__ C, int n) {
    __shared__ ushort_t As[128 * 32];
    __shared__ ushort_t Bs[128 * 32];
    const int t = threadIdx.x;
    const int lane = t & 63, wid = t >> 6;
    const int wr = wid >> 1, wc = wid & 1;
    const long brow = (long)blockIdx.x * 128;
    const int bcol = blockIdx.y * 128;

    f32x4 acc[4][4] = {};

    // staging: chunk c = wid + 4p covers rows [c*16, c*16+16); lane l -> 16B at c*1024+l*16
    const int r0 = wid * 16 + (lane >> 2);
    const int kof = (lane & 3) * 8;
    const int fr = lane & 15, kg = lane >> 4;

    for (int kt = 0; kt < 256; kt += 32) {
        __builtin_amdgcn_global_load_lds(
            (const __attribute__((address_space(1))) void*)(A + (brow + r0) * 256 + kt + kof),
            (__attribute__((address_space(3))) void*)(As + wid * 512 + lane * 8), 16, 0, 0);
        __builtin_amdgcn_global_load_lds(
            (const __attribute__((address_space(1))) void*)(A + (brow + r0 + 64) * 256 + kt + kof),
            (__attribute__((address_space(3))) void*)(As + (wid + 4) * 512 + lane * 8), 16, 0, 0);
        __builtin_amdgcn_global_load_lds(
            (const __attribute__((address_space(1))) void*)(B + (bcol + r0) * 256 + kt + kof),
            (__attribute__((address_space(3))) void*)(Bs + wid * 512 + lane * 8), 16, 0, 0);
        __builtin_amdgcn_global_load_lds(
            (const __attribute__((address_space(1))) void*)(B + (bcol + r0 + 64) * 256 + kt + kof),
            (__attribute__((address_space(3))) void*)(Bs + (wid + 4) * 512 + lane * 8), 16, 0, 0);
        asm volatile("s_waitcnt vmcnt(0)" ::: "memory");
        __syncthreads();

        s16x8 a[4], b[4];
#pragma unroll
        for (int m = 0; m < 4; m++)
            a[m] = *(const s16x8*)(As + (wr * 64 + m * 16 + fr) * 32 + kg * 8);
#pragma unroll
        for (int nn = 0; nn < 4; nn++)
            b[nn] = *(const s16x8*)(Bs + (wc * 64 + nn * 16 + fr) * 32 + kg * 8);
#pragma unroll
        for (int m = 0; m < 4; m++)
#pragma unroll
            for (int nn = 0; nn < 4; nn++)
                acc[m][nn] = __builtin_amdgcn_mfma_f32_16x16x32_bf16(a[m], b[nn], acc[m][nn], 0, 0, 0);
        __syncthreads();
    }

    const int rg = lane >> 4;
#pragma unroll
    for (int m = 0; m < 4; m++) {
        long rbase = brow + wr * 64 + m * 16 + rg * 4;
#pragma unroll
        for (int nn = 0; nn < 4; nn++) {
            int col = bcol + wc * 64 + nn * 16 + fr;
#pragma unroll
            for (int r = 0; r < 4; r++) {
                long row = rbase + r;
                if (row < n) C[row * 256 + col] = acc[m][nn][r];
            }
        }
    }
}

// ---------------- per-node attention scalars ----------------
__global__ __launch_bounds__(256) void node_att(const float* __restrict__ H,
        const float* __restrict__ att, float* __restrict__ a_dst,
        float* __restrict__ a_src, int n) {
    int w = threadIdx.x >> 6, lane = threadIdx.x & 63;
    int node = blockIdx.x * 4 + w;
    if (node >= n) return;
    float4 h4 = *(const float4*)(H + (size_t)node * 256 + lane * 4);
    float4 aL = *(const float4*)(att + lane * 4);
    float4 aH = *(const float4*)(att + 256 + lane * 4);
    float ai = h4.x * aL.x + h4.y * aL.y + h4.z * aL.z + h4.w * aL.w;
    float aj = h4.x * aH.x + h4.y * aH.y + h4.z * aH.z + h4.w * aH.w;
#pragma unroll
    for (int off = 32; off; off >>= 1) {
        ai += __shfl_xor(ai, off);
        aj += __shfl_xor(aj, off);
    }
    if (lane == 0) { a_dst[node] = ai; a_src[node] = aj; }
}

// ---------------- fused segment-softmax + weighted aggregation ----------------
// writes fp32 OUT (for pool at last layer) and bf16 copy (next layer GEMM input)
__global__ __launch_bounds__(256) void gat_agg(const float* __restrict__ H,
        const float* __restrict__ a_dst, const float* __restrict__ a_src,
        const int* __restrict__ rowptr, const int* __restrict__ adj,
        const float* __restrict__ bias, float* __restrict__ OUT,
        ushort_t* __restrict__ OUTbf, int n) {
    int w = threadIdx.x >> 6, lane = threadIdx.x & 63;
    int node = blockIdx.x * 4 + w;
    if (node >= n) return;
    int beg = rowptr[node], end = rowptr[node + 1];
    float ai = a_dst[node];

    float m = -3.4e38f;
    for (int j = beg + lane; j < end; j += 64) {
        float e = ai + a_src[adj[j]];
        e = (e > 0.f) ? e : NEG_SLOPE * e;
        m = fmaxf(m, e);
    }
#pragma unroll
    for (int off = 32; off; off >>= 1) m = fmaxf(m, __shfl_xor(m, off));

    float ssum = 0.f;
    float4 acc = make_float4(0.f, 0.f, 0.f, 0.f);
    for (int j0 = beg; j0 < end; j0 += 64) {
        int cnt = min(64, end - j0);
        int sidx = 0;
        float e = 0.f;
        if (lane < cnt) {
            sidx = adj[j0 + lane];
            float tt = ai + a_src[sidx];
            e = (tt > 0.f) ? tt : NEG_SLOPE * tt;
        }
        for (int j = 0; j < cnt; j++) {
            float ej = __shfl(e, j);
            int sj = __shfl(sidx, j);
            float wgt = expf(ej - m);
            ssum += wgt;
            float4 hv = *(const float4*)(H + (size_t)sj * 256 + lane * 4);
            acc.x = fmaf(wgt, hv.x, acc.x);
            acc.y = fmaf(wgt, hv.y, acc.y);
            acc.z = fmaf(wgt, hv.z, acc.z);
            acc.w = fmaf(wgt, hv.w, acc.w);
        }
    }
    float inv = 1.f / (ssum + 1e-16f);
    float4 b4 = *(const float4*)(bias + lane * 4);
    float4 o;
    o.x = acc.x * inv + b4.x;
    o.y = acc.y * inv + b4.y;
    o.z = acc.z * inv + b4.z;
    o.w = acc.w * inv + b4.w;
    *(float4*)(OUT + (size_t)node * 256 + lane * 4) = o;
    ushort4 ub;
    ub.x = f2bf(o.x); ub.y = f2bf(o.y); ub.z = f2bf(o.z); ub.w = f2bf(o.w);
    *(ushort4*)(OUTbf + (size_t)node * 256 + lane * 4) = ub;
}

// ---------------- relu + global max pool (batch sorted), 1024 threads ----------------
__global__ __launch_bounds__(1024) void pool_kernel(const float* __restrict__ X,
        const int* __restrict__ batch, float* __restrict__ gbuf, int n) {
    __shared__ float red[4][256];
    int g = blockIdx.x;
    int c = threadIdx.x & 255;
    int rg = threadIdx.x >> 8;
    int lo = 0, hi = n;
    while (lo < hi) { int mid = (lo + hi) >> 1; if (batch[mid] < g) lo = mid + 1; else hi = mid; }
    int start = lo;
    hi = n;
    while (lo < hi) { int mid = (lo + hi) >> 1; if (batch[mid] < g + 1) lo = mid + 1; else hi = mid; }
    int end_ = lo;
    float m = 0.f;  // relu floor
    for (int i = start + rg; i < end_; i += 4)
        m = fmaxf(m, X[(size_t)i * 256 + c]);
    red[rg][c] = m;
    __syncthreads();
    if (rg == 0) {
        m = fmaxf(fmaxf(red[0][c], red[1][c]), fmaxf(red[2][c], red[3][c]));
        gbuf[g * 256 + c] = m;
    }
}

// ---------------- post-MLP + log_softmax ----------------
__global__ __launch_bounds__(256) void final_kernel(const float* __restrict__ gbuf,
        const float* __restrict__ pW1, const float* __restrict__ pb1,
        const float* __restrict__ pW2, const float* __restrict__ pb2,
        float* __restrict__ out) {
    __shared__ float gl[256];
    __shared__ float h1[256];
    int g = blockIdx.x, t = threadIdx.x;
    gl[t] = gbuf[g * 256 + t];
    __syncthreads();
    float acc = pb1[t];
    for (int k = 0; k < 256; k++) acc = fmaf(gl[k], pW1[t * 256 + k], acc);
    h1[t] = acc;
    __syncthreads();
    if (t < 64) {
        float o = pb2[t];
        for (int k = 0; k < 256; k++) o = fmaf(h1[k], pW2[t * 256 + k], o);
        float mx = o;
#pragma unroll
        for (int off = 32; off; off >>= 1) mx = fmaxf(mx, __shfl_xor(mx, off));
        float ex = expf(o - mx);
        float s = ex;
#pragma unroll
        for (int off = 32; off; off >>= 1) s += __shfl_xor(s, off);
        out[g * 64 + t] = o - mx - logf(s);
    }
}

extern "C" void kernel_launch(void* const* d_in, const int* in_sizes, int n_in,
                              void* d_out, int out_size, void* d_ws, size_t ws_size,
                              hipStream_t stream) {
    const float* x     = (const float*)d_in[0];
    const int*   ei    = (const int*)d_in[1];
    const int*   batch = (const int*)d_in[2];
    const float* Ws    = (const float*)d_in[3];
    const float* atts  = (const float*)d_in[4];
    const float* bs    = (const float*)d_in[5];
    const float* pW1   = (const float*)d_in[6];
    const float* pb1   = (const float*)d_in[7];
    const float* pW2   = (const float*)d_in[8];
    const float* pb2   = (const float*)d_in[9];
    float* out = (float*)d_out;

    const int N = in_sizes[0] / 256;
    const int E = in_sizes[1] / 2;
    const int G = out_size / 64;
    const int L = in_sizes[3] / (256 * 256);
    const int MB = (N + 127) / 128;       // row blocks
    const int Npad = MB * 128;
    const int NT = (N + 1023) / 1024;     // scan tiles

    char* ws = (char*)d_ws;
    size_t off = 0;
    auto alloc = [&](size_t bytes) -> char* {
        char* p = ws + off;
        off += (bytes + 255) & ~size_t(255);
        return p;
    };
    float*    H      = (float*)alloc((size_t)N * 256 * 4);
    float*    OUTf   = (float*)alloc((size_t)N * 256 * 4);
    ushort_t* Xbf    = (ushort_t*)alloc((size_t)Npad * 256 * 2);
    ushort_t* Wbf    = (ushort_t*)alloc((size_t)L * 256 * 256 * 2);
    float*    a_dst  = (float*)alloc((size_t)N * 4);
    float*    a_src  = (float*)alloc((size_t)N * 4);
    int*      deg    = (int*)alloc((size_t)N * 4);
    int*      rowptr = (int*)alloc((size_t)(N + 1) * 4);
    int*      cursor = (int*)alloc((size_t)N * 4);
    int*      adj    = (int*)alloc((size_t)E * 4);
    int*      tscan  = (int*)alloc((size_t)N * 4);
    int*      bsum   = (int*)alloc((size_t)64 * 4);
    int*      boff   = (int*)alloc((size_t)64 * 4);
    float*    gbuf   = (float*)alloc((size_t)G * 256 * 4);

    // CSR build
    hipMemsetAsync(deg, 0, (size_t)N * 4, stream);
    int eb = (E + 255) / 256;
    deg_kernel<<<eb, 256, 0, stream>>>(ei, deg, E);
    scan1<<<NT, 1024, 0, stream>>>(deg, tscan, bsum, N);
    scan2<<<1, 64, 0, stream>>>(bsum, boff, NT, rowptr + N);
    scan3<<<NT, 1024, 0, stream>>>(tscan, boff, rowptr, cursor, N);
    scatter_kernel<<<eb, 256, 0, stream>>>(ei, cursor, adj, E);

    // bf16 conversions
    cvt_kernel<<<(N * 64 + 255) / 256, 256, 0, stream>>>(x, Xbf, N * 64);
    cvt_kernel<<<(L * 16384 + 255) / 256, 256, 0, stream>>>(Ws, Wbf, L * 16384);

    for (int l = 0; l < L; ++l) {
        dim3 ggrid(MB, 2);
        gemm_bf16<<<ggrid, 256, 0, stream>>>(Xbf, Wbf + (size_t)l * 65536, H, N);
        node_att<<<(N + 3) / 4, 256, 0, stream>>>(H, atts + (size_t)l * 512, a_dst, a_src, N);
        gat_agg<<<(N + 3) / 4, 256, 0, stream>>>(H, a_dst, a_src, rowptr, adj,
                                                 bs + (size_t)l * 256, OUTf, Xbf, N);
    }
    pool_kernel<<<G, 1024, 0, stream>>>(OUTf, batch, gbuf, N);
    final_kernel<<<G, 256, 0, stream>>>(gbuf, pW1, pb1, pW2, pb2, out);
}

// Round 4
// 391.818 us; speedup vs baseline: 1.9286x; 1.1328x over previous
//
#include <hip/hip_runtime.h>
#include <math.h>

#define NEG_SLOPE 0.2f

typedef __attribute__((ext_vector_type(8))) short s16x8;   // 8 bf16 (4 VGPRs)
typedef __attribute__((ext_vector_type(4))) float f32x4;
typedef unsigned short ushort_t;

__device__ inline ushort_t f2bf(float f) {
    unsigned u = __float_as_uint(f);
    unsigned r = (u + 0x7fff + ((u >> 16) & 1)) >> 16;   // RNE
    return (ushort_t)r;
}
__device__ inline float bf2f(ushort_t u) {
    return __uint_as_float(((unsigned)u) << 16);
}

// ---------------- fp32 -> bf16 conversion (4 elems/thread) ----------------
__global__ __launch_bounds__(256) void cvt_kernel(const float* __restrict__ in,
        ushort_t* __restrict__ out, int n4) {
    int i = blockIdx.x * 256 + threadIdx.x;
    if (i < n4) {
        float4 v = ((const float4*)in)[i];
        ushort4 o;
        o.x = f2bf(v.x); o.y = f2bf(v.y); o.z = f2bf(v.z); o.w = f2bf(v.w);
        ((ushort4*)out)[i] = o;
    }
}

// ---------------- CSR build ----------------
__global__ void deg_kernel(const int* __restrict__ ei, int* __restrict__ deg, int E) {
    int e = blockIdx.x * blockDim.x + threadIdx.x;
    if (e < E) atomicAdd(&deg[ei[E + e]], 1);
}

__global__ __launch_bounds__(1024) void scan1(const int* __restrict__ deg,
        int* __restrict__ tscan, int* __restrict__ bsum, int n) {
    __shared__ int ws[16];
    int t = threadIdx.x;
    int gi = blockIdx.x * 1024 + t;
    int v = (gi < n) ? deg[gi] : 0;
    int lane = t & 63, w = t >> 6;
    int s = v;
#pragma unroll
    for (int off = 1; off < 64; off <<= 1) {
        int u = __shfl_up(s, off);
        if (lane >= off) s += u;
    }
    if (lane == 63) ws[w] = s;
    __syncthreads();
    if (w == 0) {
        int x = (lane < 16) ? ws[lane] : 0;
#pragma unroll
        for (int off = 1; off < 16; off <<= 1) {
            int u = __shfl_up(x, off);
            if (lane >= off) x += u;
        }
        if (lane < 16) ws[lane] = x;
    }
    __syncthreads();
    int woff = (w > 0) ? ws[w - 1] : 0;
    if (gi < n) tscan[gi] = woff + s - v;       // exclusive within block
    if (t == 1023) bsum[blockIdx.x] = woff + s; // block total
}

__global__ void scan2(const int* __restrict__ bsum, int* __restrict__ boff,
                      int nb, int* __restrict__ total_out) {
    int lane = threadIdx.x;
    int v = (lane < nb) ? bsum[lane] : 0;
    int s = v;
#pragma unroll
    for (int off = 1; off < 64; off <<= 1) {
        int u = __shfl_up(s, off);
        if (lane >= off) s += u;
    }
    if (lane < nb) boff[lane] = s - v;
    if (lane == 63) *total_out = s;
}

__global__ __launch_bounds__(1024) void scan3(const int* __restrict__ tscan,
        const int* __restrict__ boff, int* __restrict__ rowptr,
        int* __restrict__ cursor, int n) {
    int i = blockIdx.x * 1024 + threadIdx.x;
    if (i < n) {
        int v = tscan[i] + boff[blockIdx.x];
        rowptr[i] = v;
        cursor[i] = v;
    }
}

__global__ void scatter_kernel(const int* __restrict__ ei, int* __restrict__ cursor,
                               int* __restrict__ adj, int E) {
    int e = blockIdx.x * blockDim.x + threadIdx.x;
    if (e < E) {
        int d = ei[E + e];
        int pos = atomicAdd(&cursor[d], 1);
        adj[pos] = ei[e];   // store src node id
    }
}

// ---------------- bf16 MFMA GEMM: C[n x 256] = A @ W^T, C written as bf16 ----------------
// BM=128, BN=128, BK=32, 256 threads = 4 waves (2x2), each wave 64x64 out.
__global__ __launch_bounds__(256) void gemm_bf16(const ushort_t* __restrict__ A,
        const ushort_t* __restrict__ B, ushort_t* __restrict__ C) {
    __shared__ ushort_t As[128 * 32];
    __shared__ ushort_t Bs[128 * 32];
    const int t = threadIdx.x;
    const int lane = t & 63, wid = t >> 6;
    const int wr = wid >> 1, wc = wid & 1;
    const long brow = (long)blockIdx.x * 128;
    const int bcol = blockIdx.y * 128;

    f32x4 acc[4][4] = {};

    const int r0 = wid * 16 + (lane >> 2);
    const int kof = (lane & 3) * 8;
    const int fr = lane & 15, kg = lane >> 4;

    for (int kt = 0; kt < 256; kt += 32) {
        __builtin_amdgcn_global_load_lds(
            (const __attribute__((address_space(1))) void*)(A + (brow + r0) * 256 + kt + kof),
            (__attribute__((address_space(3))) void*)(As + wid * 512 + lane * 8), 16, 0, 0);
        __builtin_amdgcn_global_load_lds(
            (const __attribute__((address_space(1))) void*)(A + (brow + r0 + 64) * 256 + kt + kof),
            (__attribute__((address_space(3))) void*)(As + (wid + 4) * 512 + lane * 8), 16, 0, 0);
        __builtin_amdgcn_global_load_lds(
            (const __attribute__((address_space(1))) void*)(B + (bcol + r0) * 256 + kt + kof),
            (__attribute__((address_space(3))) void*)(Bs + wid * 512 + lane * 8), 16, 0, 0);
        __builtin_amdgcn_global_load_lds(
            (const __attribute__((address_space(1))) void*)(B + (bcol + r0 + 64) * 256 + kt + kof),
            (__attribute__((address_space(3))) void*)(Bs + (wid + 4) * 512 + lane * 8), 16, 0, 0);
        asm volatile("s_waitcnt vmcnt(0)" ::: "memory");
        __syncthreads();

        s16x8 a[4], b[4];
#pragma unroll
        for (int m = 0; m < 4; m++)
            a[m] = *(const s16x8*)(As + (wr * 64 + m * 16 + fr) * 32 + kg * 8);
#pragma unroll
        for (int nn = 0; nn < 4; nn++)
            b[nn] = *(const s16x8*)(Bs + (wc * 64 + nn * 16 + fr) * 32 + kg * 8);
#pragma unroll
        for (int m = 0; m < 4; m++)
#pragma unroll
            for (int nn = 0; nn < 4; nn++)
                acc[m][nn] = __builtin_amdgcn_mfma_f32_16x16x32_bf16(a[m], b[nn], acc[m][nn], 0, 0, 0);
        __syncthreads();
    }

    const int rg = lane >> 4;
#pragma unroll
    for (int m = 0; m < 4; m++) {
        long rbase = brow + wr * 64 + m * 16 + rg * 4;
#pragma unroll
        for (int nn = 0; nn < 4; nn++) {
            int col = bcol + wc * 64 + nn * 16 + fr;
#pragma unroll
            for (int r = 0; r < 4; r++)
                C[(rbase + r) * 256 + col] = f2bf(acc[m][nn][r]);
        }
    }
}

// ---------------- per-node attention scalars (bf16 input) ----------------
__global__ __launch_bounds__(256) void node_att(const ushort_t* __restrict__ H,
        const float* __restrict__ att, float* __restrict__ a_dst,
        float* __restrict__ a_src, int n) {
    int w = threadIdx.x >> 6, lane = threadIdx.x & 63;
    int node = blockIdx.x * 4 + w;
    if (node >= n) return;
    ushort4 h4 = *(const ushort4*)(H + (size_t)node * 256 + lane * 4);
    float4 aL = *(const float4*)(att + lane * 4);
    float4 aH = *(const float4*)(att + 256 + lane * 4);
    float hx = bf2f(h4.x), hy = bf2f(h4.y), hz = bf2f(h4.z), hw = bf2f(h4.w);
    float ai = hx * aL.x + hy * aL.y + hz * aL.z + hw * aL.w;
    float aj = hx * aH.x + hy * aH.y + hz * aH.z + hw * aH.w;
#pragma unroll
    for (int off = 32; off; off >>= 1) {
        ai += __shfl_xor(ai, off);
        aj += __shfl_xor(aj, off);
    }
    if (lane == 0) { a_dst[node] = ai; a_src[node] = aj; }
}

// ---------------- fused segment-softmax + weighted aggregation (bf16 gather) ----------------
__global__ __launch_bounds__(256) void gat_agg(const ushort_t* __restrict__ H,
        const float* __restrict__ a_dst, const float* __restrict__ a_src,
        const int* __restrict__ rowptr, const int* __restrict__ adj,
        const float* __restrict__ bias, float* __restrict__ OUT,
        ushort_t* __restrict__ OUTbf, int n, int write_f32) {
    int w = threadIdx.x >> 6, lane = threadIdx.x & 63;
    int node = blockIdx.x * 4 + w;
    if (node >= n) return;
    int beg = rowptr[node], end = rowptr[node + 1];
    float ai = a_dst[node];

    float m = -3.4e38f;
    for (int j = beg + lane; j < end; j += 64) {
        float e = ai + a_src[adj[j]];
        e = (e > 0.f) ? e : NEG_SLOPE * e;
        m = fmaxf(m, e);
    }
#pragma unroll
    for (int off = 32; off; off >>= 1) m = fmaxf(m, __shfl_xor(m, off));

    float ssum = 0.f;
    float4 acc = make_float4(0.f, 0.f, 0.f, 0.f);
    for (int j0 = beg; j0 < end; j0 += 64) {
        int cnt = min(64, end - j0);
        int sidx = 0;
        float e = 0.f;
        if (lane < cnt) {
            sidx = adj[j0 + lane];
            float tt = ai + a_src[sidx];
            e = (tt > 0.f) ? tt : NEG_SLOPE * tt;
        }
        for (int j = 0; j < cnt; j++) {
            float ej = __shfl(e, j);
            int sj = __shfl(sidx, j);
            float wgt = expf(ej - m);
            ssum += wgt;
            ushort4 hv = *(const ushort4*)(H + (size_t)sj * 256 + lane * 4);
            acc.x = fmaf(wgt, bf2f(hv.x), acc.x);
            acc.y = fmaf(wgt, bf2f(hv.y), acc.y);
            acc.z = fmaf(wgt, bf2f(hv.z), acc.z);
            acc.w = fmaf(wgt, bf2f(hv.w), acc.w);
        }
    }
    float inv = 1.f / (ssum + 1e-16f);
    float4 b4 = *(const float4*)(bias + lane * 4);
    float4 o;
    o.x = acc.x * inv + b4.x;
    o.y = acc.y * inv + b4.y;
    o.z = acc.z * inv + b4.z;
    o.w = acc.w * inv + b4.w;
    if (write_f32)
        *(float4*)(OUT + (size_t)node * 256 + lane * 4) = o;
    ushort4 ub;
    ub.x = f2bf(o.x); ub.y = f2bf(o.y); ub.z = f2bf(o.z); ub.w = f2bf(o.w);
    *(ushort4*)(OUTbf + (size_t)node * 256 + lane * 4) = ub;
}

// ---------------- relu + global max pool (batch sorted), 1024 threads ----------------
__global__ __launch_bounds__(1024) void pool_kernel(const float* __restrict__ X,
        const int* __restrict__ batch, float* __restrict__ gbuf, int n) {
    __shared__ float red[4][256];
    int g = blockIdx.x;
    int c = threadIdx.x & 255;
    int rg = threadIdx.x >> 8;
    int lo = 0, hi = n;
    while (lo < hi) { int mid = (lo + hi) >> 1; if (batch[mid] < g) lo = mid + 1; else hi = mid; }
    int start = lo;
    hi = n;
    while (lo < hi) { int mid = (lo + hi) >> 1; if (batch[mid] < g + 1) lo = mid + 1; else hi = mid; }
    int end_ = lo;
    float m = 0.f;  // relu floor
    for (int i = start + rg; i < end_; i += 4)
        m = fmaxf(m, X[(size_t)i * 256 + c]);
    red[rg][c] = m;
    __syncthreads();
    if (rg == 0) {
        m = fmaxf(fmaxf(red[0][c], red[1][c]), fmaxf(red[2][c], red[3][c]));
        gbuf[g * 256 + c] = m;
    }
}

// ---------------- post-MLP + log_softmax ----------------
__global__ __launch_bounds__(256) void final_kernel(const float* __restrict__ gbuf,
        const float* __restrict__ pW1, const float* __restrict__ pb1,
        const float* __restrict__ pW2, const float* __restrict__ pb2,
        float* __restrict__ out) {
    __shared__ float gl[256];
    __shared__ float h1[256];
    int g = blockIdx.x, t = threadIdx.x;
    gl[t] = gbuf[g * 256 + t];
    __syncthreads();
    float acc = pb1[t];
    for (int k = 0; k < 256; k++) acc = fmaf(gl[k], pW1[t * 256 + k], acc);
    h1[t] = acc;
    __syncthreads();
    if (t < 64) {
        float o = pb2[t];
        for (int k = 0; k < 256; k++) o = fmaf(h1[k], pW2[t * 256 + k], o);
        float mx = o;
#pragma unroll
        for (int off = 32; off; off >>= 1) mx = fmaxf(mx, __shfl_xor(mx, off));
        float ex = expf(o - mx);
        float s = ex;
#pragma unroll
        for (int off = 32; off; off >>= 1) s += __shfl_xor(s, off);
        out[g * 64 + t] = o - mx - logf(s);
    }
}

extern "C" void kernel_launch(void* const* d_in, const int* in_sizes, int n_in,
                              void* d_out, int out_size, void* d_ws, size_t ws_size,
                              hipStream_t stream) {
    const float* x     = (const float*)d_in[0];
    const int*   ei    = (const int*)d_in[1];
    const int*   batch = (const int*)d_in[2];
    const float* Ws    = (const float*)d_in[3];
    const float* atts  = (const float*)d_in[4];
    const float* bs    = (const float*)d_in[5];
    const float* pW1   = (const float*)d_in[6];
    const float* pb1   = (const float*)d_in[7];
    const float* pW2   = (const float*)d_in[8];
    const float* pb2   = (const float*)d_in[9];
    float* out = (float*)d_out;

    const int N = in_sizes[0] / 256;
    const int E = in_sizes[1] / 2;
    const int G = out_size / 64;
    const int L = in_sizes[3] / (256 * 256);
    const int MB = (N + 127) / 128;       // row blocks
    const int Npad = MB * 128;
    const int NT = (N + 1023) / 1024;     // scan tiles

    char* ws = (char*)d_ws;
    size_t off = 0;
    auto alloc = [&](size_t bytes) -> char* {
        char* p = ws + off;
        off += (bytes + 255) & ~size_t(255);
        return p;
    };
    ushort_t* Hbf    = (ushort_t*)alloc((size_t)Npad * 256 * 2);
    float*    OUTf   = (float*)alloc((size_t)N * 256 * 4);
    ushort_t* Xbf    = (ushort_t*)alloc((size_t)Npad * 256 * 2);
    ushort_t* Wbf    = (ushort_t*)alloc((size_t)L * 256 * 256 * 2);
    float*    a_dst  = (float*)alloc((size_t)N * 4);
    float*    a_src  = (float*)alloc((size_t)N * 4);
    int*      deg    = (int*)alloc((size_t)N * 4);
    int*      rowptr = (int*)alloc((size_t)(N + 1) * 4);
    int*      cursor = (int*)alloc((size_t)N * 4);
    int*      adj    = (int*)alloc((size_t)E * 4);
    int*      tscan  = (int*)alloc((size_t)N * 4);
    int*      bsum   = (int*)alloc((size_t)64 * 4);
    int*      boff   = (int*)alloc((size_t)64 * 4);
    float*    gbuf   = (float*)alloc((size_t)G * 256 * 4);

    // CSR build
    hipMemsetAsync(deg, 0, (size_t)N * 4, stream);
    int eb = (E + 255) / 256;
    deg_kernel<<<eb, 256, 0, stream>>>(ei, deg, E);
    scan1<<<NT, 1024, 0, stream>>>(deg, tscan, bsum, N);
    scan2<<<1, 64, 0, stream>>>(bsum, boff, NT, rowptr + N);
    scan3<<<NT, 1024, 0, stream>>>(tscan, boff, rowptr, cursor, N);
    scatter_kernel<<<eb, 256, 0, stream>>>(ei, cursor, adj, E);

    // bf16 conversions
    cvt_kernel<<<(N * 64 + 255) / 256, 256, 0, stream>>>(x, Xbf, N * 64);
    cvt_kernel<<<(L * 16384 + 255) / 256, 256, 0, stream>>>(Ws, Wbf, L * 16384);

    for (int l = 0; l < L; ++l) {
        dim3 ggrid(MB, 2);
        gemm_bf16<<<ggrid, 256, 0, stream>>>(Xbf, Wbf + (size_t)l * 65536, Hbf);
        node_att<<<(N + 3) / 4, 256, 0, stream>>>(Hbf, atts + (size_t)l * 512, a_dst, a_src, N);
        gat_agg<<<(N + 3) / 4, 256, 0, stream>>>(Hbf, a_dst, a_src, rowptr, adj,
                                                 bs + (size_t)l * 256, OUTf, Xbf, N,
                                                 (l == L - 1) ? 1 : 0);
    }
    pool_kernel<<<G, 1024, 0, stream>>>(OUTf, batch, gbuf, N);
    final_kernel<<<G, 256, 0, stream>>>(gbuf, pW1, pb1, pW2, pb2, out);
}

// Round 8
// 368.328 us; speedup vs baseline: 2.0516x; 1.0638x over previous
//
#include <hip/hip_runtime.h>
#include <math.h>

#define NEG_SLOPE 0.2f

typedef __attribute__((ext_vector_type(8))) short s16x8;   // 8 bf16 (4 VGPRs)
typedef __attribute__((ext_vector_type(4))) float f32x4;
typedef unsigned short ushort_t;
typedef unsigned int uint_t;

__device__ inline ushort_t f2bf(float f) {
    unsigned u = __float_as_uint(f);
    unsigned r = (u + 0x7fff + ((u >> 16) & 1)) >> 16;   // RNE
    return (ushort_t)r;
}
__device__ inline float bf2f(ushort_t u) {
    return __uint_as_float(((unsigned)u) << 16);
}

// ---------------- fp32 -> bf16 conversion (4 elems/thread) ----------------
__global__ __launch_bounds__(256) void cvt_kernel(const float* __restrict__ in,
        ushort_t* __restrict__ out, int n4) {
    int i = blockIdx.x * 256 + threadIdx.x;
    if (i < n4) {
        float4 v = ((const float4*)in)[i];
        ushort4 o;
        o.x = f2bf(v.x); o.y = f2bf(v.y); o.z = f2bf(v.z); o.w = f2bf(v.w);
        ((ushort4*)out)[i] = o;
    }
}

// ---------------- CSR build ----------------
__global__ void deg_kernel(const int* __restrict__ ei, int* __restrict__ deg, int E) {
    int e = blockIdx.x * blockDim.x + threadIdx.x;
    if (e < E) atomicAdd(&deg[ei[E + e]], 1);
}

__global__ __launch_bounds__(1024) void scan1(const int* __restrict__ deg,
        int* __restrict__ tscan, int* __restrict__ bsum, int n) {
    __shared__ int ws[16];
    int t = threadIdx.x;
    int gi = blockIdx.x * 1024 + t;
    int v = (gi < n) ? deg[gi] : 0;
    int lane = t & 63, w = t >> 6;
    int s = v;
#pragma unroll
    for (int off = 1; off < 64; off <<= 1) {
        int u = __shfl_up(s, off);
        if (lane >= off) s += u;
    }
    if (lane == 63) ws[w] = s;
    __syncthreads();
    if (w == 0) {
        int x = (lane < 16) ? ws[lane] : 0;
#pragma unroll
        for (int off = 1; off < 16; off <<= 1) {
            int u = __shfl_up(x, off);
            if (lane >= off) x += u;
        }
        if (lane < 16) ws[lane] = x;
    }
    __syncthreads();
    int woff = (w > 0) ? ws[w - 1] : 0;
    if (gi < n) tscan[gi] = woff + s - v;       // exclusive within block
    if (t == 1023) bsum[blockIdx.x] = woff + s; // block total
}

__global__ void scan2(const int* __restrict__ bsum, int* __restrict__ boff,
                      int nb, int* __restrict__ total_out) {
    int lane = threadIdx.x;
    int v = (lane < nb) ? bsum[lane] : 0;
    int s = v;
#pragma unroll
    for (int off = 1; off < 64; off <<= 1) {
        int u = __shfl_up(s, off);
        if (lane >= off) s += u;
    }
    if (lane < nb) boff[lane] = s - v;
    if (lane == 63) *total_out = s;
}

__global__ __launch_bounds__(1024) void scan3(const int* __restrict__ tscan,
        const int* __restrict__ boff, int* __restrict__ rowptr,
        int* __restrict__ cursor, int n) {
    int i = blockIdx.x * 1024 + threadIdx.x;
    if (i < n) {
        int v = tscan[i] + boff[blockIdx.x];
        rowptr[i] = v;
        cursor[i] = v;
    }
}

__global__ void scatter_kernel(const int* __restrict__ ei, int* __restrict__ cursor,
                               int* __restrict__ adj, int E) {
    int e = blockIdx.x * blockDim.x + threadIdx.x;
    if (e < E) {
        int d = ei[E + e];
        int pos = atomicAdd(&cursor[d], 1);
        adj[pos] = ei[e];   // store src node id
    }
}

// ---------------- bf16 MFMA GEMM + fused attention dots ----------------
// C[n x 256] = A @ W^T (bf16 out). Also atomically accumulates
// a_dst[row] += dot(C_row, att[0:256]), a_src[row] += dot(C_row, att[256:512]).
// BM=128, BN=128, BK=32, 256 threads = 4 waves (2x2), each wave 64x64 out.
__global__ __launch_bounds__(256) void gemm_bf16(const ushort_t* __restrict__ A,
        const ushort_t* __restrict__ B, ushort_t* __restrict__ C,
        const float* __restrict__ att, float* __restrict__ a_dst,
        float* __restrict__ a_src, int n) {
    __shared__ ushort_t As[128 * 32];
    __shared__ ushort_t Bs[128 * 32];
    const int t = threadIdx.x;
    const int lane = t & 63, wid = t >> 6;
    const int wr = wid >> 1, wc = wid & 1;
    const long brow = (long)blockIdx.x * 128;
    const int bcol = blockIdx.y * 128;

    f32x4 acc[4][4] = {};

    const int r0 = wid * 16 + (lane >> 2);
    const int kof = (lane & 3) * 8;
    const int fr = lane & 15, kg = lane >> 4;

    for (int kt = 0; kt < 256; kt += 32) {
        __builtin_amdgcn_global_load_lds(
            (const __attribute__((address_space(1))) void*)(A + (brow + r0) * 256 + kt + kof),
            (__attribute__((address_space(3))) void*)(As + wid * 512 + lane * 8), 16, 0, 0);
        __builtin_amdgcn_global_load_lds(
            (const __attribute__((address_space(1))) void*)(A + (brow + r0 + 64) * 256 + kt + kof),
            (__attribute__((address_space(3))) void*)(As + (wid + 4) * 512 + lane * 8), 16, 0, 0);
        __builtin_amdgcn_global_load_lds(
            (const __attribute__((address_space(1))) void*)(B + (bcol + r0) * 256 + kt + kof),
            (__attribute__((address_space(3))) void*)(Bs + wid * 512 + lane * 8), 16, 0, 0);
        __builtin_amdgcn_global_load_lds(
            (const __attribute__((address_space(1))) void*)(B + (bcol + r0 + 64) * 256 + kt + kof),
            (__attribute__((address_space(3))) void*)(Bs + (wid + 4) * 512 + lane * 8), 16, 0, 0);
        asm volatile("s_waitcnt vmcnt(0)" ::: "memory");
        __syncthreads();

        s16x8 a[4], b[4];
#pragma unroll
        for (int m = 0; m < 4; m++)
            a[m] = *(const s16x8*)(As + (wr * 64 + m * 16 + fr) * 32 + kg * 8);
#pragma unroll
        for (int nn = 0; nn < 4; nn++)
            b[nn] = *(const s16x8*)(Bs + (wc * 64 + nn * 16 + fr) * 32 + kg * 8);
#pragma unroll
        for (int m = 0; m < 4; m++)
#pragma unroll
            for (int nn = 0; nn < 4; nn++)
                acc[m][nn] = __builtin_amdgcn_mfma_f32_16x16x32_bf16(a[m], b[nn], acc[m][nn], 0, 0, 0);
        __syncthreads();
    }

    const int rg = lane >> 4;
    const float* attL = att;
    const float* attR = att + 256;
#pragma unroll
    for (int m = 0; m < 4; m++) {
        long rbase = brow + wr * 64 + m * 16 + rg * 4;
#pragma unroll
        for (int r = 0; r < 4; r++) {
            long row = rbase + r;
            float sL = 0.f, sR = 0.f;
#pragma unroll
            for (int nn = 0; nn < 4; nn++) {
                int col = bcol + wc * 64 + nn * 16 + fr;
                float v = acc[m][nn][r];
                C[row * 256 + col] = f2bf(v);
                sL = fmaf(v, attL[col], sL);
                sR = fmaf(v, attR[col], sR);
            }
#pragma unroll
            for (int off = 8; off; off >>= 1) {
                sL += __shfl_xor(sL, off);
                sR += __shfl_xor(sR, off);
            }
            if (fr == 0 && row < n) {
                atomicAdd(&a_dst[row], sL);
                atomicAdd(&a_src[row], sR);
            }
        }
    }
}

// ---------------- fused segment-softmax + weighted aggregation ----------------
// One wave per dst node. Pass 2: 4 edge-groups x 16 feature-lanes, 32 B/lane loads.
__global__ __launch_bounds__(256) void gat_agg(const ushort_t* __restrict__ H,
        const float* __restrict__ a_dst, const float* __restrict__ a_src,
        const int* __restrict__ rowptr, const int* __restrict__ adj,
        const float* __restrict__ bias, ushort_t* __restrict__ OUTbf, int n) {
    int w = threadIdx.x >> 6, lane = threadIdx.x & 63;
    int node = blockIdx.x * 4 + w;
    if (node >= n) return;
    int beg = rowptr[node], end = rowptr[node + 1];
    float ai = a_dst[node];

    // pass 1: segment max (64-lane edge-parallel)
    float m = -3.4e38f;
    for (int j = beg + lane; j < end; j += 64) {
        float e = ai + a_src[adj[j]];
        e = (e > 0.f) ? e : NEG_SLOPE * e;
        m = fmaxf(m, e);
    }
#pragma unroll
    for (int off = 32; off; off >>= 1) m = fmaxf(m, __shfl_xor(m, off));

    // pass 2: group g handles edge j0+g; lane fl covers features [fl*16, fl*16+16)
    const int g = lane >> 4, fl = lane & 15;
    float ssum = 0.f;
    float acc[16];
#pragma unroll
    for (int k = 0; k < 16; k++) acc[k] = 0.f;

    for (int j0 = beg; j0 < end; j0 += 4) {
        int j = j0 + g;
        if (j < end) {
            int sidx = adj[j];
            float tt = ai + a_src[sidx];
            tt = (tt > 0.f) ? tt : NEG_SLOPE * tt;
            float wgt = expf(tt - m);
            ssum += wgt;
            const ushort_t* hp = H + (size_t)sidx * 256 + fl * 16;
            uint4 q0 = *(const uint4*)(hp);
            uint4 q1 = *(const uint4*)(hp + 8);
            uint_t qs[8] = {q0.x, q0.y, q0.z, q0.w, q1.x, q1.y, q1.z, q1.w};
#pragma unroll
            for (int k = 0; k < 8; k++) {
                float flo = __uint_as_float(qs[k] << 16);
                float fhi = __uint_as_float(qs[k] & 0xffff0000u);
                acc[2 * k]     = fmaf(wgt, flo, acc[2 * k]);
                acc[2 * k + 1] = fmaf(wgt, fhi, acc[2 * k + 1]);
            }
        }
    }

    // cross-group reduce (groups differ in lane bits 4,5)
#pragma unroll
    for (int k = 0; k < 16; k++) {
        acc[k] += __shfl_xor(acc[k], 16);
        acc[k] += __shfl_xor(acc[k], 32);
    }
    ssum += __shfl_xor(ssum, 16);
    ssum += __shfl_xor(ssum, 32);

    if (g == 0) {
        float inv = 1.f / (ssum + 1e-16f);
        float bv[16];
        *(float4*)&bv[0]  = *(const float4*)(bias + fl * 16);
        *(float4*)&bv[4]  = *(const float4*)(bias + fl * 16 + 4);
        *(float4*)&bv[8]  = *(const float4*)(bias + fl * 16 + 8);
        *(float4*)&bv[12] = *(const float4*)(bias + fl * 16 + 12);
        uint_t ou[8];
#pragma unroll
        for (int k = 0; k < 8; k++) {
            uint_t lo = f2bf(acc[2 * k] * inv + bv[2 * k]);
            uint_t hi = f2bf(acc[2 * k + 1] * inv + bv[2 * k + 1]);
            ou[k] = lo | (hi << 16);
        }
        uint4* op = (uint4*)(OUTbf + (size_t)node * 256 + fl * 16);
        op[0] = make_uint4(ou[0], ou[1], ou[2], ou[3]);
        op[1] = make_uint4(ou[4], ou[5], ou[6], ou[7]);
    }
}

// ---------------- relu + global max pool from bf16 (batch sorted) ----------------
__global__ __launch_bounds__(1024) void pool_kernel(const ushort_t* __restrict__ X,
        const int* __restrict__ batch, float* __restrict__ gbuf, int n) {
    __shared__ float red[4][256];
    int g = blockIdx.x;
    int c = threadIdx.x & 255;
    int rg = threadIdx.x >> 8;
    int lo = 0, hi = n;
    while (lo < hi) { int mid = (lo + hi) >> 1; if (batch[mid] < g) lo = mid + 1; else hi = mid; }
    int start = lo;
    hi = n;
    while (lo < hi) { int mid = (lo + hi) >> 1; if (batch[mid] < g + 1) lo = mid + 1; else hi = mid; }
    int end_ = lo;
    float m = 0.f;  // relu floor
    for (int i = start + rg; i < end_; i += 4)
        m = fmaxf(m, bf2f(X[(size_t)i * 256 + c]));
    red[rg][c] = m;
    __syncthreads();
    if (rg == 0) {
        m = fmaxf(fmaxf(red[0][c], red[1][c]), fmaxf(red[2][c], red[3][c]));
        gbuf[g * 256 + c] = m;
    }
}

// ---------------- post-MLP + log_softmax ----------------
__global__ __launch_bounds__(256) void final_kernel(const float* __restrict__ gbuf,
        const float* __restrict__ pW1, const float* __restrict__ pb1,
        const float* __restrict__ pW2, const float* __restrict__ pb2,
        float* __restrict__ out) {
    __shared__ float gl[256];
    __shared__ float h1[256];
    int g = blockIdx.x, t = threadIdx.x;
    gl[t] = gbuf[g * 256 + t];
    __syncthreads();
    float acc = pb1[t];
    for (int k = 0; k < 256; k++) acc = fmaf(gl[k], pW1[t * 256 + k], acc);
    h1[t] = acc;
    __syncthreads();
    if (t < 64) {
        float o = pb2[t];
        for (int k = 0; k < 256; k++) o = fmaf(h1[k], pW2[t * 256 + k], o);
        float mx = o;
#pragma unroll
        for (int off = 32; off; off >>= 1) mx = fmaxf(mx, __shfl_xor(mx, off));
        float ex = expf(o - mx);
        float s = ex;
#pragma unroll
        for (int off = 32; off; off >>= 1) s += __shfl_xor(s, off);
        out[g * 64 + t] = o - mx - logf(s);
    }
}

extern "C" void kernel_launch(void* const* d_in, const int* in_sizes, int n_in,
                              void* d_out, int out_size, void* d_ws, size_t ws_size,
                              hipStream_t stream) {
    const float* x     = (const float*)d_in[0];
    const int*   ei    = (const int*)d_in[1];
    const int*   batch = (const int*)d_in[2];
    const float* Ws    = (const float*)d_in[3];
    const float* atts  = (const float*)d_in[4];
    const float* bs    = (const float*)d_in[5];
    const float* pW1   = (const float*)d_in[6];
    const float* pb1   = (const float*)d_in[7];
    const float* pW2   = (const float*)d_in[8];
    const float* pb2   = (const float*)d_in[9];
    float* out = (float*)d_out;

    const int N = in_sizes[0] / 256;
    const int E = in_sizes[1] / 2;
    const int G = out_size / 64;
    const int L = in_sizes[3] / (256 * 256);
    const int MB = (N + 127) / 128;       // row blocks
    const int Npad = MB * 128;
    const int NT = (N + 1023) / 1024;     // scan tiles

    char* ws = (char*)d_ws;
    size_t off = 0;
    auto alloc = [&](size_t bytes) -> char* {
        char* p = ws + off;
        off += (bytes + 255) & ~size_t(255);
        return p;
    };
    ushort_t* Hbf    = (ushort_t*)alloc((size_t)Npad * 256 * 2);
    ushort_t* Xbf    = (ushort_t*)alloc((size_t)Npad * 256 * 2);
    ushort_t* Wbf    = (ushort_t*)alloc((size_t)L * 256 * 256 * 2);
    float*    a_both = (float*)alloc((size_t)2 * N * 4);
    float*    a_dst  = a_both;
    float*    a_src  = a_both + N;
    int*      deg    = (int*)alloc((size_t)N * 4);
    int*      rowptr = (int*)alloc((size_t)(N + 1) * 4);
    int*      cursor = (int*)alloc((size_t)N * 4);
    int*      adj    = (int*)alloc((size_t)E * 4);
    int*      tscan  = (int*)alloc((size_t)N * 4);
    int*      bsum   = (int*)alloc((size_t)64 * 4);
    int*      boff   = (int*)alloc((size_t)64 * 4);
    float*    gbuf   = (float*)alloc((size_t)G * 256 * 4);

    // CSR build
    hipMemsetAsync(deg, 0, (size_t)N * 4, stream);
    int eb = (E + 255) / 256;
    deg_kernel<<<eb, 256, 0, stream>>>(ei, deg, E);
    scan1<<<NT, 1024, 0, stream>>>(deg, tscan, bsum, N);
    scan2<<<1, 64, 0, stream>>>(bsum, boff, NT, rowptr + N);
    scan3<<<NT, 1024, 0, stream>>>(tscan, boff, rowptr, cursor, N);
    scatter_kernel<<<eb, 256, 0, stream>>>(ei, cursor, adj, E);

    // bf16 conversions
    cvt_kernel<<<(N * 64 + 255) / 256, 256, 0, stream>>>(x, Xbf, N * 64);
    cvt_kernel<<<(L * 16384 + 255) / 256, 256, 0, stream>>>(Ws, Wbf, L * 16384);

    for (int l = 0; l < L; ++l) {
        hipMemsetAsync(a_both, 0, (size_t)2 * N * 4, stream);
        dim3 ggrid(MB, 2);
        gemm_bf16<<<ggrid, 256, 0, stream>>>(Xbf, Wbf + (size_t)l * 65536, Hbf,
                                             atts + (size_t)l * 512, a_dst, a_src, N);
        gat_agg<<<(N + 3) / 4, 256, 0, stream>>>(Hbf, a_dst, a_src, rowptr, adj,
                                                 bs + (size_t)l * 256, Xbf, N);
    }
    pool_kernel<<<G, 1024, 0, stream>>>(Xbf, batch, gbuf, N);
    final_kernel<<<G, 256, 0, stream>>>(gbuf, pW1, pb1, pW2, pb2, out);
}

// Round 9
// 351.610 us; speedup vs baseline: 2.1491x; 1.0475x over previous
//
#include <hip/hip_runtime.h>
#include <math.h>

#define NEG_SLOPE 0.2f

typedef __attribute__((ext_vector_type(8))) short s16x8;   // 8 bf16 (4 VGPRs)
typedef __attribute__((ext_vector_type(4))) float f32x4;
typedef unsigned short ushort_t;
typedef unsigned int uint_t;

__device__ inline ushort_t f2bf(float f) {
    unsigned u = __float_as_uint(f);
    unsigned r = (u + 0x7fff + ((u >> 16) & 1)) >> 16;   // RNE
    return (ushort_t)r;
}
__device__ inline float bf2f(ushort_t u) {
    return __uint_as_float(((unsigned)u) << 16);
}

// ---------------- fused fp32 -> bf16 conversion for two arrays ----------------
__global__ __launch_bounds__(256) void cvt2_kernel(const float* __restrict__ a,
        ushort_t* __restrict__ oa, int na4,
        const float* __restrict__ b, ushort_t* __restrict__ ob, int nb4) {
    int i = blockIdx.x * 256 + threadIdx.x;
    if (i < na4) {
        float4 v = ((const float4*)a)[i];
        ushort4 o;
        o.x = f2bf(v.x); o.y = f2bf(v.y); o.z = f2bf(v.z); o.w = f2bf(v.w);
        ((ushort4*)oa)[i] = o;
    } else if (i - na4 < nb4) {
        int k = i - na4;
        float4 v = ((const float4*)b)[k];
        ushort4 o;
        o.x = f2bf(v.x); o.y = f2bf(v.y); o.z = f2bf(v.z); o.w = f2bf(v.w);
        ((ushort4*)ob)[k] = o;
    }
}

// ---------------- CSR build ----------------
__global__ void deg_kernel(const int* __restrict__ ei, int* __restrict__ deg, int E) {
    int e = blockIdx.x * blockDim.x + threadIdx.x;
    if (e < E) atomicAdd(&deg[ei[E + e]], 1);
}

__global__ __launch_bounds__(1024) void scan1(const int* __restrict__ deg,
        int* __restrict__ tscan, int* __restrict__ bsum, int n) {
    __shared__ int ws[16];
    int t = threadIdx.x;
    int gi = blockIdx.x * 1024 + t;
    int v = (gi < n) ? deg[gi] : 0;
    int lane = t & 63, w = t >> 6;
    int s = v;
#pragma unroll
    for (int off = 1; off < 64; off <<= 1) {
        int u = __shfl_up(s, off);
        if (lane >= off) s += u;
    }
    if (lane == 63) ws[w] = s;
    __syncthreads();
    if (w == 0) {
        int x = (lane < 16) ? ws[lane] : 0;
#pragma unroll
        for (int off = 1; off < 16; off <<= 1) {
            int u = __shfl_up(x, off);
            if (lane >= off) x += u;
        }
        if (lane < 16) ws[lane] = x;
    }
    __syncthreads();
    int woff = (w > 0) ? ws[w - 1] : 0;
    if (gi < n) tscan[gi] = woff + s - v;       // exclusive within block
    if (t == 1023) bsum[blockIdx.x] = woff + s; // block total
}

// scan3 now also does the block-offset scan internally (nb <= 64) and writes rowptr[n].
__global__ __launch_bounds__(1024) void scan3(const int* __restrict__ tscan,
        const int* __restrict__ bsum, const int* __restrict__ deg,
        int* __restrict__ rowptr, int* __restrict__ cursor, int n, int nb) {
    __shared__ int sboff;
    int t = threadIdx.x;
    if (t < 64) {
        int v = (t < nb) ? bsum[t] : 0;
        int s = v;
#pragma unroll
        for (int off = 1; off < 64; off <<= 1) {
            int u = __shfl_up(s, off);
            if (t >= off) s += u;
        }
        if (t == (int)blockIdx.x) sboff = s - v;   // exclusive prefix for this block
    }
    __syncthreads();
    int i = blockIdx.x * 1024 + t;
    if (i < n) {
        int v = tscan[i] + sboff;
        rowptr[i] = v;
        cursor[i] = v;
        if (i == n - 1) rowptr[n] = v + deg[i];
    }
}

__global__ void scatter_kernel(const int* __restrict__ ei, int* __restrict__ cursor,
                               int* __restrict__ adj, int E) {
    int e = blockIdx.x * blockDim.x + threadIdx.x;
    if (e < E) {
        int d = ei[E + e];
        int pos = atomicAdd(&cursor[d], 1);
        adj[pos] = ei[e];   // store src node id
    }
}

// ---------------- bf16 MFMA GEMM + fused attention dots ----------------
// C[n x 256] = A @ W^T (bf16 out). Also atomically accumulates
// a_dst[row] += dot(C_row, att[0:256]), a_src[row] += dot(C_row, att[256:512]).
// BM=128, BN=128, BK=32, 256 threads = 4 waves (2x2), each wave 64x64 out.
__global__ __launch_bounds__(256) void gemm_bf16(const ushort_t* __restrict__ A,
        const ushort_t* __restrict__ B, ushort_t* __restrict__ C,
        const float* __restrict__ att, float* __restrict__ a_dst,
        float* __restrict__ a_src, int n) {
    __shared__ ushort_t As[128 * 32];
    __shared__ ushort_t Bs[128 * 32];
    const int t = threadIdx.x;
    const int lane = t & 63, wid = t >> 6;
    const int wr = wid >> 1, wc = wid & 1;
    const long brow = (long)blockIdx.x * 128;
    const int bcol = blockIdx.y * 128;

    f32x4 acc[4][4] = {};

    const int r0 = wid * 16 + (lane >> 2);
    const int kof = (lane & 3) * 8;
    const int fr = lane & 15, kg = lane >> 4;

    for (int kt = 0; kt < 256; kt += 32) {
        __builtin_amdgcn_global_load_lds(
            (const __attribute__((address_space(1))) void*)(A + (brow + r0) * 256 + kt + kof),
            (__attribute__((address_space(3))) void*)(As + wid * 512 + lane * 8), 16, 0, 0);
        __builtin_amdgcn_global_load_lds(
            (const __attribute__((address_space(1))) void*)(A + (brow + r0 + 64) * 256 + kt + kof),
            (__attribute__((address_space(3))) void*)(As + (wid + 4) * 512 + lane * 8), 16, 0, 0);
        __builtin_amdgcn_global_load_lds(
            (const __attribute__((address_space(1))) void*)(B + (bcol + r0) * 256 + kt + kof),
            (__attribute__((address_space(3))) void*)(Bs + wid * 512 + lane * 8), 16, 0, 0);
        __builtin_amdgcn_global_load_lds(
            (const __attribute__((address_space(1))) void*)(B + (bcol + r0 + 64) * 256 + kt + kof),
            (__attribute__((address_space(3))) void*)(Bs + (wid + 4) * 512 + lane * 8), 16, 0, 0);
        asm volatile("s_waitcnt vmcnt(0)" ::: "memory");
        __syncthreads();

        s16x8 a[4], b[4];
#pragma unroll
        for (int m = 0; m < 4; m++)
            a[m] = *(const s16x8*)(As + (wr * 64 + m * 16 + fr) * 32 + kg * 8);
#pragma unroll
        for (int nn = 0; nn < 4; nn++)
            b[nn] = *(const s16x8*)(Bs + (wc * 64 + nn * 16 + fr) * 32 + kg * 8);
#pragma unroll
        for (int m = 0; m < 4; m++)
#pragma unroll
            for (int nn = 0; nn < 4; nn++)
                acc[m][nn] = __builtin_amdgcn_mfma_f32_16x16x32_bf16(a[m], b[nn], acc[m][nn], 0, 0, 0);
        __syncthreads();
    }

    const int rg = lane >> 4;
    const float* attL = att;
    const float* attR = att + 256;
#pragma unroll
    for (int m = 0; m < 4; m++) {
        long rbase = brow + wr * 64 + m * 16 + rg * 4;
#pragma unroll
        for (int r = 0; r < 4; r++) {
            long row = rbase + r;
            float sL = 0.f, sR = 0.f;
#pragma unroll
            for (int nn = 0; nn < 4; nn++) {
                int col = bcol + wc * 64 + nn * 16 + fr;
                float v = acc[m][nn][r];
                C[row * 256 + col] = f2bf(v);
                sL = fmaf(v, attL[col], sL);
                sR = fmaf(v, attR[col], sR);
            }
#pragma unroll
            for (int off = 8; off; off >>= 1) {
                sL += __shfl_xor(sL, off);
                sR += __shfl_xor(sR, off);
            }
            if (fr == 0 && row < n) {
                atomicAdd(&a_dst[row], sL);
                atomicAdd(&a_src[row], sR);
            }
        }
    }
}

// ---------------- fused segment-softmax + weighted aggregation ----------------
// One wave per dst node. Fast path (deg<=64): adjacency + e cached in registers
// from pass 1, pass 2 gets them via shfl. Pass 2: 4 edge-groups x 16 lanes.
__global__ __launch_bounds__(256) void gat_agg(const ushort_t* __restrict__ H,
        const float* __restrict__ a_dst, const float* __restrict__ a_src,
        const int* __restrict__ rowptr, const int* __restrict__ adj,
        const float* __restrict__ bias, ushort_t* __restrict__ OUTbf, int n) {
    int w = threadIdx.x >> 6, lane = threadIdx.x & 63;
    int node = blockIdx.x * 4 + w;
    if (node >= n) return;
    int beg = rowptr[node], end = rowptr[node + 1];
    int degree = end - beg;
    float ai = a_dst[node];

    const int g = lane >> 4, fl = lane & 15;
    float ssum = 0.f;
    float acc[16];
#pragma unroll
    for (int k = 0; k < 16; k++) acc[k] = 0.f;
    float m;

    if (degree <= 64) {
        // pass 1: lane j caches edge beg+j
        int sidx_c = 0;
        float e_c = -3.4e38f;
        if (lane < degree) {
            sidx_c = adj[beg + lane];
            float tt = ai + a_src[sidx_c];
            e_c = (tt > 0.f) ? tt : NEG_SLOPE * tt;
        }
        m = e_c;
#pragma unroll
        for (int off = 32; off; off >>= 1) m = fmaxf(m, __shfl_xor(m, off));

        // pass 2 via shfl broadcast
        for (int j0 = 0; j0 < degree; j0 += 4) {
            int j = j0 + g;
            if (j < degree) {
                float ej = __shfl(e_c, j);
                int sj = __shfl(sidx_c, j);
                float wgt = expf(ej - m);
                ssum += wgt;
                const ushort_t* hp = H + (size_t)sj * 256 + fl * 16;
                uint4 q0 = *(const uint4*)(hp);
                uint4 q1 = *(const uint4*)(hp + 8);
                uint_t qs[8] = {q0.x, q0.y, q0.z, q0.w, q1.x, q1.y, q1.z, q1.w};
#pragma unroll
                for (int k = 0; k < 8; k++) {
                    float flo = __uint_as_float(qs[k] << 16);
                    float fhi = __uint_as_float(qs[k] & 0xffff0000u);
                    acc[2 * k]     = fmaf(wgt, flo, acc[2 * k]);
                    acc[2 * k + 1] = fmaf(wgt, fhi, acc[2 * k + 1]);
                }
            }
        }
    } else {
        // generic fallback
        m = -3.4e38f;
        for (int j = beg + lane; j < end; j += 64) {
            float e = ai + a_src[adj[j]];
            e = (e > 0.f) ? e : NEG_SLOPE * e;
            m = fmaxf(m, e);
        }
#pragma unroll
        for (int off = 32; off; off >>= 1) m = fmaxf(m, __shfl_xor(m, off));

        for (int j0 = beg; j0 < end; j0 += 4) {
            int j = j0 + g;
            if (j < end) {
                int sidx = adj[j];
                float tt = ai + a_src[sidx];
                tt = (tt > 0.f) ? tt : NEG_SLOPE * tt;
                float wgt = expf(tt - m);
                ssum += wgt;
                const ushort_t* hp = H + (size_t)sidx * 256 + fl * 16;
                uint4 q0 = *(const uint4*)(hp);
                uint4 q1 = *(const uint4*)(hp + 8);
                uint_t qs[8] = {q0.x, q0.y, q0.z, q0.w, q1.x, q1.y, q1.z, q1.w};
#pragma unroll
                for (int k = 0; k < 8; k++) {
                    float flo = __uint_as_float(qs[k] << 16);
                    float fhi = __uint_as_float(qs[k] & 0xffff0000u);
                    acc[2 * k]     = fmaf(wgt, flo, acc[2 * k]);
                    acc[2 * k + 1] = fmaf(wgt, fhi, acc[2 * k + 1]);
                }
            }
        }
    }

    // cross-group reduce (groups differ in lane bits 4,5)
#pragma unroll
    for (int k = 0; k < 16; k++) {
        acc[k] += __shfl_xor(acc[k], 16);
        acc[k] += __shfl_xor(acc[k], 32);
    }
    ssum += __shfl_xor(ssum, 16);
    ssum += __shfl_xor(ssum, 32);

    if (g == 0) {
        float inv = 1.f / (ssum + 1e-16f);
        float bv[16];
        *(float4*)&bv[0]  = *(const float4*)(bias + fl * 16);
        *(float4*)&bv[4]  = *(const float4*)(bias + fl * 16 + 4);
        *(float4*)&bv[8]  = *(const float4*)(bias + fl * 16 + 8);
        *(float4*)&bv[12] = *(const float4*)(bias + fl * 16 + 12);
        uint_t ou[8];
#pragma unroll
        for (int k = 0; k < 8; k++) {
            uint_t lo = f2bf(acc[2 * k] * inv + bv[2 * k]);
            uint_t hi = f2bf(acc[2 * k + 1] * inv + bv[2 * k + 1]);
            ou[k] = lo | (hi << 16);
        }
        uint4* op = (uint4*)(OUTbf + (size_t)node * 256 + fl * 16);
        op[0] = make_uint4(ou[0], ou[1], ou[2], ou[3]);
        op[1] = make_uint4(ou[4], ou[5], ou[6], ou[7]);
    }
}

// ---------------- relu + global max pool from bf16 (batch sorted) ----------------
__global__ __launch_bounds__(1024) void pool_kernel(const ushort_t* __restrict__ X,
        const int* __restrict__ batch, float* __restrict__ gbuf, int n) {
    __shared__ float red[4][256];
    int g = blockIdx.x;
    int c = threadIdx.x & 255;
    int rg = threadIdx.x >> 8;
    int lo = 0, hi = n;
    while (lo < hi) { int mid = (lo + hi) >> 1; if (batch[mid] < g) lo = mid + 1; else hi = mid; }
    int start = lo;
    hi = n;
    while (lo < hi) { int mid = (lo + hi) >> 1; if (batch[mid] < g + 1) lo = mid + 1; else hi = mid; }
    int end_ = lo;
    float m = 0.f;  // relu floor
    for (int i = start + rg; i < end_; i += 4)
        m = fmaxf(m, bf2f(X[(size_t)i * 256 + c]));
    red[rg][c] = m;
    __syncthreads();
    if (rg == 0) {
        m = fmaxf(fmaxf(red[0][c], red[1][c]), fmaxf(red[2][c], red[3][c]));
        gbuf[g * 256 + c] = m;
    }
}

// ---------------- post-MLP + log_softmax ----------------
__global__ __launch_bounds__(256) void final_kernel(const float* __restrict__ gbuf,
        const float* __restrict__ pW1, const float* __restrict__ pb1,
        const float* __restrict__ pW2, const float* __restrict__ pb2,
        float* __restrict__ out) {
    __shared__ float gl[256];
    __shared__ float h1[256];
    int g = blockIdx.x, t = threadIdx.x;
    gl[t] = gbuf[g * 256 + t];
    __syncthreads();
    float acc = pb1[t];
    for (int k = 0; k < 256; k++) acc = fmaf(gl[k], pW1[t * 256 + k], acc);
    h1[t] = acc;
    __syncthreads();
    if (t < 64) {
        float o = pb2[t];
        for (int k = 0; k < 256; k++) o = fmaf(h1[k], pW2[t * 256 + k], o);
        float mx = o;
#pragma unroll
        for (int off = 32; off; off >>= 1) mx = fmaxf(mx, __shfl_xor(mx, off));
        float ex = expf(o - mx);
        float s = ex;
#pragma unroll
        for (int off = 32; off; off >>= 1) s += __shfl_xor(s, off);
        out[g * 64 + t] = o - mx - logf(s);
    }
}

extern "C" void kernel_launch(void* const* d_in, const int* in_sizes, int n_in,
                              void* d_out, int out_size, void* d_ws, size_t ws_size,
                              hipStream_t stream) {
    const float* x     = (const float*)d_in[0];
    const int*   ei    = (const int*)d_in[1];
    const int*   batch = (const int*)d_in[2];
    const float* Ws    = (const float*)d_in[3];
    const float* atts  = (const float*)d_in[4];
    const float* bs    = (const float*)d_in[5];
    const float* pW1   = (const float*)d_in[6];
    const float* pb1   = (const float*)d_in[7];
    const float* pW2   = (const float*)d_in[8];
    const float* pb2   = (const float*)d_in[9];
    float* out = (float*)d_out;

    const int N = in_sizes[0] / 256;
    const int E = in_sizes[1] / 2;
    const int G = out_size / 64;
    const int L = in_sizes[3] / (256 * 256);
    const int MB = (N + 127) / 128;       // row blocks
    const int Npad = MB * 128;
    const int NT = (N + 1023) / 1024;     // scan tiles

    char* ws = (char*)d_ws;
    size_t off = 0;
    auto alloc = [&](size_t bytes) -> char* {
        char* p = ws + off;
        off += (bytes + 255) & ~size_t(255);
        return p;
    };
    ushort_t* Hbf    = (ushort_t*)alloc((size_t)Npad * 256 * 2);
    ushort_t* Xbf    = (ushort_t*)alloc((size_t)Npad * 256 * 2);
    ushort_t* Wbf    = (ushort_t*)alloc((size_t)L * 256 * 256 * 2);
    // zero region: deg + per-layer a_dst/a_src (contiguous; one memset)
    char*     zbeg   = ws + off;
    int*      deg    = (int*)alloc((size_t)N * 4);
    float*    a_all  = (float*)alloc((size_t)L * 2 * N * 4);
    size_t    zlen   = (size_t)((ws + off) - zbeg);
    int*      rowptr = (int*)alloc((size_t)(N + 1) * 4);
    int*      cursor = (int*)alloc((size_t)N * 4);
    int*      adj    = (int*)alloc((size_t)E * 4);
    int*      tscan  = (int*)alloc((size_t)N * 4);
    int*      bsum   = (int*)alloc((size_t)64 * 4);
    float*    gbuf   = (float*)alloc((size_t)G * 256 * 4);

    // one memset for deg + all attention scalar accumulators
    hipMemsetAsync(zbeg, 0, zlen, stream);

    // CSR build
    int eb = (E + 255) / 256;
    deg_kernel<<<eb, 256, 0, stream>>>(ei, deg, E);
    scan1<<<NT, 1024, 0, stream>>>(deg, tscan, bsum, N);
    scan3<<<NT, 1024, 0, stream>>>(tscan, bsum, deg, rowptr, cursor, N, NT);
    scatter_kernel<<<eb, 256, 0, stream>>>(ei, cursor, adj, E);

    // bf16 conversions (x and Ws in one launch)
    int na4 = N * 64, nb4 = L * 16384;
    cvt2_kernel<<<(na4 + nb4 + 255) / 256, 256, 0, stream>>>(x, Xbf, na4, Ws, Wbf, nb4);

    for (int l = 0; l < L; ++l) {
        float* a_dst = a_all + (size_t)l * 2 * N;
        float* a_src = a_dst + N;
        dim3 ggrid(MB, 2);
        gemm_bf16<<<ggrid, 256, 0, stream>>>(Xbf, Wbf + (size_t)l * 65536, Hbf,
                                             atts + (size_t)l * 512, a_dst, a_src, N);
        gat_agg<<<(N + 3) / 4, 256, 0, stream>>>(Hbf, a_dst, a_src, rowptr, adj,
                                                 bs + (size_t)l * 256, Xbf, N);
    }
    pool_kernel<<<G, 1024, 0, stream>>>(Xbf, batch, gbuf, N);
    final_kernel<<<G, 256, 0, stream>>>(gbuf, pW1, pb1, pW2, pb2, out);
}